// Round 2
// baseline (14089.601 us; speedup 1.0000x reference)
//
#include <hip/hip_runtime.h>
#include <hip/hip_bf16.h>

#define D_MODEL 1024
#define SEQ     512
#define NBATCH  4
#define NHEAD   16
#define HDIM    64
#define NTOK    2048          // NBATCH*SEQ
#define VOCAB   32000
#define FFDIM   4096
#define SV      16384000ull   // SEQ*VOCAB

// ---------------- block reduction helpers (256 threads = 4 waves) ----------
__device__ __forceinline__ float block_sum(float v, float* lds) {
    #pragma unroll
    for (int o = 1; o < 64; o <<= 1) v += __shfl_xor(v, o);
    int w = threadIdx.x >> 6;
    if ((threadIdx.x & 63) == 0) lds[w] = v;
    __syncthreads();
    v = lds[0] + lds[1] + lds[2] + lds[3];
    __syncthreads();
    return v;
}
__device__ __forceinline__ float block_max(float v, float* lds) {
    #pragma unroll
    for (int o = 1; o < 64; o <<= 1) v = fmaxf(v, __shfl_xor(v, o));
    int w = threadIdx.x >> 6;
    if ((threadIdx.x & 63) == 0) lds[w] = v;
    __syncthreads();
    v = fmaxf(fmaxf(lds[0], lds[1]), fmaxf(lds[2], lds[3]));
    __syncthreads();
    return v;
}

// ---------------- embedding + sinusoidal posenc ----------------------------
__global__ __launch_bounds__(256) void embed_kernel(
    const int* __restrict__ text, const float* __restrict__ We,
    float* __restrict__ X)
{
    int t = blockIdx.x;            // token row 0..2047
    int s = t & (SEQ - 1);         // position in sequence
    int tok = text[t];
    int tid = threadIdx.x;
    const float kf = 9.210340371976184f / 1024.f;   // ln(10000)/D
    #pragma unroll
    for (int e = 0; e < 4; e++) {
        int d = tid + e * 256;
        int i2 = d & ~1;
        float freq = expf(-(float)i2 * kf);
        float ang = (float)s * freq;
        float pe = (d & 1) ? cosf(ang) : sinf(ang);
        X[(size_t)t * D_MODEL + d] = We[(size_t)tok * D_MODEL + d] + pe;
    }
}

// ---------------- GEMM: C(M,N) = A(M,K) @ W(N,K)^T + bias, opt ReLU --------
// 64x64 tile, BK=16, 256 threads, 4x4 per thread. All dims divide exactly.
template<bool RELU>
__global__ __launch_bounds__(256) void gemm_bias_kernel(
    const float* __restrict__ A, const float* __restrict__ W,
    const float* __restrict__ bias, float* __restrict__ C,
    int M, int N, int K)
{
    __shared__ float As[16][65];
    __shared__ float Bs[16][65];
    const int tid = threadIdx.x;
    const int tx = tid & 15;
    const int ty = tid >> 4;
    const int m0 = blockIdx.y * 64;
    const int n0 = blockIdx.x * 64;
    float acc[4][4] = {};
    for (int k0 = 0; k0 < K; k0 += 16) {
        #pragma unroll
        for (int e = 0; e < 4; e++) {
            int idx = tid + e * 256;       // 0..1023
            int r = idx >> 4, kk = idx & 15;
            As[kk][r] = A[(size_t)(m0 + r) * K + k0 + kk];
            Bs[kk][r] = W[(size_t)(n0 + r) * K + k0 + kk];
        }
        __syncthreads();
        #pragma unroll
        for (int kk = 0; kk < 16; kk++) {
            float a[4], b[4];
            #pragma unroll
            for (int i = 0; i < 4; i++) a[i] = As[kk][ty * 4 + i];
            #pragma unroll
            for (int j = 0; j < 4; j++) b[j] = Bs[kk][tx * 4 + j];
            #pragma unroll
            for (int i = 0; i < 4; i++)
                #pragma unroll
                for (int j = 0; j < 4; j++)
                    acc[i][j] = fmaf(a[i], b[j], acc[i][j]);
        }
        __syncthreads();
    }
    #pragma unroll
    for (int j = 0; j < 4; j++) {
        float bj = bias[n0 + tx * 4 + j];
        #pragma unroll
        for (int i = 0; i < 4; i++) {
            float v = acc[i][j] + bj;
            if (RELU) v = fmaxf(v, 0.f);
            C[(size_t)(m0 + ty * 4 + i) * N + n0 + tx * 4 + j] = v;
        }
    }
}

// ---------------- attention scores: Sc(bh,q,k) = Q·K^T * scale (+mask) -----
// grid (Sk/32, Sq/32, B*H), 256 threads, 2x2 per thread over a 32x32 tile
__global__ __launch_bounds__(256) void attn_scores_kernel(
    const float* __restrict__ Q, const float* __restrict__ Kb,
    float* __restrict__ Sc, int causal)
{
    __shared__ float Qs[32][65];
    __shared__ float Ks[32][65];
    int bh = blockIdx.z;
    int b = bh >> 4, h = bh & 15;
    int q0 = blockIdx.y * 32, k0 = blockIdx.x * 32;
    const int tid = threadIdx.x;
    const float* Qbase = Q + (size_t)(b * SEQ + q0) * D_MODEL + h * HDIM;
    const float* Kbase = Kb + (size_t)(b * SEQ + k0) * D_MODEL + h * HDIM;
    #pragma unroll
    for (int e = 0; e < 8; e++) {
        int idx = tid + e * 256;
        int r = idx >> 6, d = idx & 63;
        Qs[r][d] = Qbase[(size_t)r * D_MODEL + d];
        Ks[r][d] = Kbase[(size_t)r * D_MODEL + d];
    }
    __syncthreads();
    int tx = tid & 15, ty = tid >> 4;
    float acc[2][2] = {};
    #pragma unroll 8
    for (int d = 0; d < 64; d++) {
        float a0 = Qs[ty * 2][d],     a1 = Qs[ty * 2 + 1][d];
        float b0 = Ks[tx * 2][d],     b1 = Ks[tx * 2 + 1][d];
        acc[0][0] = fmaf(a0, b0, acc[0][0]);
        acc[0][1] = fmaf(a0, b1, acc[0][1]);
        acc[1][0] = fmaf(a1, b0, acc[1][0]);
        acc[1][1] = fmaf(a1, b1, acc[1][1]);
    }
    #pragma unroll
    for (int i = 0; i < 2; i++)
        #pragma unroll
        for (int j = 0; j < 2; j++) {
            int qq = q0 + ty * 2 + i;
            int kk = k0 + tx * 2 + j;
            float v = acc[i][j] * 0.125f;   // 1/sqrt(64)
            if (causal && kk > qq) v = -1e30f;
            Sc[((size_t)bh * SEQ + qq) * SEQ + kk] = v;
        }
}

// ---------------- row softmax over 512 (in place) --------------------------
__global__ __launch_bounds__(256) void softmax_row_kernel(float* __restrict__ Sc)
{
    __shared__ float lds[4];
    size_t row = blockIdx.x;
    float* p = Sc + row * SEQ;
    int tid = threadIdx.x;
    float v0 = p[tid], v1 = p[tid + 256];
    float m = block_max(fmaxf(v0, v1), lds);
    float e0 = expf(v0 - m), e1 = expf(v1 - m);
    float s = block_sum(e0 + e1, lds);
    float inv = 1.f / s;
    p[tid] = e0 * inv;
    p[tid + 256] = e1 * inv;
}

// ---------------- O(bh, q, :) = W(q,k) @ V(k, d) ---------------------------
// grid (Sq/32, B*H), 256 threads, tile 32q x 64d, 2x4 per thread
__global__ __launch_bounds__(256) void attn_av_kernel(
    const float* __restrict__ Sc, const float* __restrict__ V,
    float* __restrict__ O)
{
    __shared__ float Ws[32][33];
    __shared__ float Vs[32][65];
    int bh = blockIdx.y;
    int b = bh >> 4, h = bh & 15;
    int q0 = blockIdx.x * 32;
    int tid = threadIdx.x;
    int tx = tid & 15, ty = tid >> 4;
    float acc[2][4] = {};
    for (int k0 = 0; k0 < SEQ; k0 += 32) {
        #pragma unroll
        for (int e = 0; e < 4; e++) {
            int idx = tid + e * 256;
            int r = idx >> 5, c = idx & 31;
            Ws[r][c] = Sc[((size_t)bh * SEQ + q0 + r) * SEQ + k0 + c];
        }
        #pragma unroll
        for (int e = 0; e < 8; e++) {
            int idx = tid + e * 256;
            int r = idx >> 6, d = idx & 63;
            Vs[r][d] = V[(size_t)(b * SEQ + k0 + r) * D_MODEL + h * HDIM + d];
        }
        __syncthreads();
        #pragma unroll
        for (int kk = 0; kk < 32; kk++) {
            float a0 = Ws[ty * 2][kk], a1 = Ws[ty * 2 + 1][kk];
            float bv[4];
            #pragma unroll
            for (int j = 0; j < 4; j++) bv[j] = Vs[kk][tx * 4 + j];
            #pragma unroll
            for (int j = 0; j < 4; j++) {
                acc[0][j] = fmaf(a0, bv[j], acc[0][j]);
                acc[1][j] = fmaf(a1, bv[j], acc[1][j]);
            }
        }
        __syncthreads();
    }
    #pragma unroll
    for (int i = 0; i < 2; i++)
        #pragma unroll
        for (int j = 0; j < 4; j++)
            O[(size_t)(b * SEQ + q0 + ty * 2 + i) * D_MODEL + h * HDIM + tx * 4 + j] = acc[i][j];
}

// ---------------- fused residual add + LayerNorm ---------------------------
__global__ __launch_bounds__(256) void add_ln_kernel(
    const float* __restrict__ X, const float* __restrict__ Y,
    const float* __restrict__ g, const float* __restrict__ bb,
    float* __restrict__ Out)
{
    __shared__ float lds[4];
    int row = blockIdx.x;
    const float* xp = X + (size_t)row * D_MODEL;
    const float* yp = Y + (size_t)row * D_MODEL;
    int tid = threadIdx.x;
    float s[4];
    float lsum = 0.f;
    #pragma unroll
    for (int e = 0; e < 4; e++) {
        int d = tid + e * 256;
        s[e] = xp[d] + yp[d];
        lsum += s[e];
    }
    float mu = block_sum(lsum, lds) * (1.f / D_MODEL);
    float lv = 0.f;
    #pragma unroll
    for (int e = 0; e < 4; e++) { float t = s[e] - mu; lv += t * t; }
    float rstd = rsqrtf(block_sum(lv, lds) * (1.f / D_MODEL) + 1e-5f);
    #pragma unroll
    for (int e = 0; e < 4; e++) {
        int d = tid + e * 256;
        Out[(size_t)row * D_MODEL + d] = (s[e] - mu) * rstd * g[d] + bb[d];
    }
}

// ---------------- softmax over axis 0 (batch of 4) -------------------------
__global__ __launch_bounds__(256) void softmax_axis0_kernel(
    const float* __restrict__ L, float* __restrict__ out)
{
    size_t idx = (size_t)blockIdx.x * 256 + threadIdx.x;
    if (idx >= SV) return;
    float v0 = L[idx], v1 = L[idx + SV], v2 = L[idx + 2 * SV], v3 = L[idx + 3 * SV];
    float m = fmaxf(fmaxf(v0, v1), fmaxf(v2, v3));
    float e0 = expf(v0 - m), e1 = expf(v1 - m), e2 = expf(v2 - m), e3 = expf(v3 - m);
    float inv = 1.f / (e0 + e1 + e2 + e3);
    out[idx]           = e0 * inv;
    out[idx + SV]      = e1 * inv;
    out[idx + 2 * SV]  = e2 * inv;
    out[idx + 3 * SV]  = e3 * inv;
}

// ===========================================================================
extern "C" void kernel_launch(void* const* d_in, const int* in_sizes, int n_in,
                              void* d_out, int out_size, void* d_ws, size_t ws_size,
                              hipStream_t stream)
{
    const int*   text = (const int*)d_in[0];
    const float* enc  = (const float*)d_in[1];
    const float* W_e  = (const float*)d_in[2];
    const float* b_out= (const float*)d_in[3];
    const float* ln_g = (const float*)d_in[4];
    const float* ln_b = (const float*)d_in[5];
    const float* W1   = (const float*)d_in[6];
    const float* b1   = (const float*)d_in[7];
    const float* W2   = (const float*)d_in[8];
    const float* b2   = (const float*)d_in[9];
    const float* mWq  = (const float*)d_in[10]; const float* mbq = (const float*)d_in[11];
    const float* mWk  = (const float*)d_in[12]; const float* mbk = (const float*)d_in[13];
    const float* mWv  = (const float*)d_in[14]; const float* mbv = (const float*)d_in[15];
    const float* mWo  = (const float*)d_in[16]; const float* mbo = (const float*)d_in[17];
    const float* cWq  = (const float*)d_in[18]; const float* cbq = (const float*)d_in[19];
    const float* cWk  = (const float*)d_in[20]; const float* cbk = (const float*)d_in[21];
    const float* cWv  = (const float*)d_in[22]; const float* cbv = (const float*)d_in[23];
    const float* cWo  = (const float*)d_in[24]; const float* cbo = (const float*)d_in[25];
    float* out = (float*)d_out;

    // workspace carve-up (floats).
    // Layer-loop layout: x | a c q kbuf vbuf attn o enck encv | Sc | ffh
    // Final phase: logits (250 MB) ALIASES everything after x (only x live).
    const size_t ACT = (size_t)NTOK * D_MODEL;      // 2M floats
    float* base = (float*)d_ws;
    float* x    = base;
    float* a    = x    + ACT;
    float* c    = a    + ACT;
    float* q    = c    + ACT;
    float* kbuf = q    + ACT;
    float* vbuf = kbuf + ACT;
    float* attn = vbuf + ACT;
    float* o    = attn + ACT;
    float* enck = o    + ACT;
    float* encv = enck + ACT;
    float* Sc   = encv + ACT;                       // 64 bh * 512 * 512
    float* ffh  = Sc   + (size_t)NBATCH * NHEAD * SEQ * SEQ;   // 2048*4096
    float* logits = a;                              // aliases layer scratch

    auto gemm = [&](const float* A, const float* W, const float* bias, float* C,
                    int M, int N, int K, bool relu) {
        dim3 grid(N / 64, M / 64);
        if (relu)
            gemm_bias_kernel<true><<<grid, 256, 0, stream>>>(A, W, bias, C, M, N, K);
        else
            gemm_bias_kernel<false><<<grid, 256, 0, stream>>>(A, W, bias, C, M, N, K);
    };

    // 1. embed + posenc
    embed_kernel<<<NTOK, 256, 0, stream>>>(text, W_e, x);

    // 2. encoder K/V (fixed across layers) — enc is fp32, used directly
    gemm(enc, cWk, cbk, enck, NTOK, D_MODEL, D_MODEL, false);
    gemm(enc, cWv, cbv, encv, NTOK, D_MODEL, D_MODEL, false);

    const int BH = NBATCH * NHEAD;   // 64
    for (int layer = 0; layer < 6; layer++) {
        // --- self attention (causal) ---
        gemm(x, mWq, mbq, q,    NTOK, D_MODEL, D_MODEL, false);
        gemm(x, mWk, mbk, kbuf, NTOK, D_MODEL, D_MODEL, false);
        gemm(x, mWv, mbv, vbuf, NTOK, D_MODEL, D_MODEL, false);
        attn_scores_kernel<<<dim3(SEQ / 32, SEQ / 32, BH), 256, 0, stream>>>(q, kbuf, Sc, 1);
        softmax_row_kernel<<<BH * SEQ, 256, 0, stream>>>(Sc);
        attn_av_kernel<<<dim3(SEQ / 32, BH), 256, 0, stream>>>(Sc, vbuf, attn);
        gemm(attn, mWo, mbo, o, NTOK, D_MODEL, D_MODEL, false);
        add_ln_kernel<<<NTOK, 256, 0, stream>>>(x, o, ln_g, ln_b, a);

        // --- cross attention ---
        gemm(a, cWq, cbq, q, NTOK, D_MODEL, D_MODEL, false);
        attn_scores_kernel<<<dim3(SEQ / 32, SEQ / 32, BH), 256, 0, stream>>>(q, enck, Sc, 0);
        softmax_row_kernel<<<BH * SEQ, 256, 0, stream>>>(Sc);
        attn_av_kernel<<<dim3(SEQ / 32, BH), 256, 0, stream>>>(Sc, encv, attn);
        gemm(attn, cWo, cbo, o, NTOK, D_MODEL, D_MODEL, false);
        add_ln_kernel<<<NTOK, 256, 0, stream>>>(o, a, ln_g, ln_b, c);

        // --- FFN ---
        gemm(c, W1, b1, ffh, NTOK, FFDIM, D_MODEL, true);
        gemm(ffh, W2, b2, o, NTOK, D_MODEL, FFDIM, false);
        add_ln_kernel<<<NTOK, 256, 0, stream>>>(c, o, ln_g, ln_b, x);
    }

    // final logits + axis-0 softmax (logits aliases layer scratch; x is live)
    gemm(x, W_e, b_out, logits, NTOK, VOCAB, D_MODEL, false);
    softmax_axis0_kernel<<<(int)((SV + 255) / 256), 256, 0, stream>>>(logits, out);
}

// Round 3
// 4641.526 us; speedup vs baseline: 3.0356x; 3.0356x over previous
//
#include <hip/hip_runtime.h>

#define D_MODEL 1024
#define SEQ     512
#define NBATCH  4
#define NHEAD   16
#define HDIM    64
#define NTOK    2048          // NBATCH*SEQ
#define VOCAB   32000
#define FFDIM   4096
#define VCHUNK  6400          // vocab chunk for logits (5 chunks)
#define MiB     (1024*1024)

typedef _Float16 f16;
typedef f16   f16x8 __attribute__((ext_vector_type(8)));
typedef float f32x4 __attribute__((ext_vector_type(4)));

// async 16B global->LDS copy (direct-to-shared DMA)
__device__ __forceinline__ void async_cp16(f16* lds, const f16* g) {
    __builtin_amdgcn_global_load_lds(
        (const __attribute__((address_space(1))) unsigned int*)g,
        (__attribute__((address_space(3))) unsigned int*)lds, 16, 0, 0);
}

// ---------------- block reduction helpers (256 threads = 4 waves) ----------
__device__ __forceinline__ float block_sum(float v, float* lds) {
    #pragma unroll
    for (int o = 1; o < 64; o <<= 1) v += __shfl_xor(v, o);
    int w = threadIdx.x >> 6;
    if ((threadIdx.x & 63) == 0) lds[w] = v;
    __syncthreads();
    v = lds[0] + lds[1] + lds[2] + lds[3];
    __syncthreads();
    return v;
}
__device__ __forceinline__ float block_max(float v, float* lds) {
    #pragma unroll
    for (int o = 1; o < 64; o <<= 1) v = fmaxf(v, __shfl_xor(v, o));
    int w = threadIdx.x >> 6;
    if ((threadIdx.x & 63) == 0) lds[w] = v;
    __syncthreads();
    v = fmaxf(fmaxf(lds[0], lds[1]), fmaxf(lds[2], lds[3]));
    __syncthreads();
    return v;
}

// ---------------- fp32 -> fp16 convert -------------------------------------
__global__ __launch_bounds__(256) void f32_to_f16_kernel(
    const float* __restrict__ in, f16* __restrict__ out, int n)
{
    int i0 = blockIdx.x * 1024 + threadIdx.x;
    #pragma unroll
    for (int e = 0; e < 4; e++) {
        int i = i0 + e * 256;
        if (i < n) out[i] = (f16)in[i];
    }
}

// ---------------- embedding + sinusoidal posenc (f32 + f16 out) ------------
__global__ __launch_bounds__(256) void embed_kernel(
    const int* __restrict__ text, const float* __restrict__ We,
    float* __restrict__ X, f16* __restrict__ X16)
{
    int t = blockIdx.x;            // token row 0..2047
    int s = t & (SEQ - 1);         // position in sequence
    int tok = text[t];
    int tid = threadIdx.x;
    const float kf = 9.210340371976184f / 1024.f;   // ln(10000)/D
    #pragma unroll
    for (int e = 0; e < 4; e++) {
        int d = tid + e * 256;
        int i2 = d & ~1;
        float freq = expf(-(float)i2 * kf);
        float ang = (float)s * freq;
        float pe = (d & 1) ? cosf(ang) : sinf(ang);
        float v = We[(size_t)tok * D_MODEL + d] + pe;
        X[(size_t)t * D_MODEL + d] = v;
        X16[(size_t)t * D_MODEL + d] = (f16)v;
    }
}

// ---------------- fp16 MFMA GEMM: C(M,N)=A(M,K)@W(N,K)^T + bias ------------
// 128x128 tile, BK=32, 256 threads (4 waves, each 64x64 = 4x4 MFMA tiles).
// OUTMODE: 0 = f32 out, 1 = f16 out. RELU optional.
template<bool RELU, int OUTMODE>
__global__ __launch_bounds__(256) void gemm16_kernel(
    const f16* __restrict__ A, const f16* __restrict__ W,
    const float* __restrict__ bias, float* __restrict__ C,
    f16* __restrict__ C16, int M, int N, int K)
{
    __shared__ __align__(16) f16 As[128 * 32];
    __shared__ __align__(16) f16 Bs[128 * 32];
    const int tid  = threadIdx.x;
    const int lane = tid & 63;
    const int wv   = tid >> 6;
    const int wr   = (wv >> 1) * 64;   // wave row offset in tile
    const int wc   = (wv & 1) * 64;    // wave col offset in tile
    const int m0 = blockIdx.y * 128;
    const int n0 = blockIdx.x * 128;
    const int lm = lane & 15;          // fragment row/col within 16x16 tile
    const int lk = (lane >> 4) * 8;    // fragment k offset

    f32x4 acc[4][4] = {};

    for (int k0 = 0; k0 < K; k0 += 32) {
        #pragma unroll
        for (int e = 0; e < 2; e++) {
            int s = tid + e * 256;          // 0..511
            int row = s >> 2, cb = s & 3;   // tile row, 8-elem col block
            async_cp16(&As[s * 8], &A[(size_t)(m0 + row) * K + k0 + cb * 8]);
            async_cp16(&Bs[s * 8], &W[(size_t)(n0 + row) * K + k0 + cb * 8]);
        }
        __syncthreads();
        f16x8 af[4], bfr[4];
        #pragma unroll
        for (int i = 0; i < 4; i++) {
            af[i]  = *(const f16x8*)&As[(wr + i * 16 + lm) * 32 + lk];
            bfr[i] = *(const f16x8*)&Bs[(wc + i * 16 + lm) * 32 + lk];
        }
        #pragma unroll
        for (int i = 0; i < 4; i++)
            #pragma unroll
            for (int j = 0; j < 4; j++)
                acc[i][j] = __builtin_amdgcn_mfma_f32_16x16x32_f16(
                    af[i], bfr[j], acc[i][j], 0, 0, 0);
        __syncthreads();
    }

    const int rq = (lane >> 4) * 4;
    #pragma unroll
    for (int i = 0; i < 4; i++) {
        #pragma unroll
        for (int j = 0; j < 4; j++) {
            int col = n0 + wc + j * 16 + lm;
            float bj = bias[col];
            #pragma unroll
            for (int r = 0; r < 4; r++) {
                int row = m0 + wr + i * 16 + rq + r;
                float v = acc[i][j][r] + bj;
                if (RELU) v = fmaxf(v, 0.f);
                if (OUTMODE == 0) C[(size_t)row * N + col] = v;
                else              C16[(size_t)row * N + col] = (f16)v;
            }
        }
    }
}

// ---------------- attention scores: Sc(bh,q,k) = Q·K^T * scale (+mask) -----
__global__ __launch_bounds__(256) void attn_scores_kernel(
    const float* __restrict__ Q, const float* __restrict__ Kb,
    float* __restrict__ Sc, int causal)
{
    __shared__ float Qs[32][65];
    __shared__ float Ks[32][65];
    int bh = blockIdx.z;
    int b = bh >> 4, h = bh & 15;
    int q0 = blockIdx.y * 32, k0 = blockIdx.x * 32;
    const int tid = threadIdx.x;
    const float* Qbase = Q + (size_t)(b * SEQ + q0) * D_MODEL + h * HDIM;
    const float* Kbase = Kb + (size_t)(b * SEQ + k0) * D_MODEL + h * HDIM;
    #pragma unroll
    for (int e = 0; e < 8; e++) {
        int idx = tid + e * 256;
        int r = idx >> 6, d = idx & 63;
        Qs[r][d] = Qbase[(size_t)r * D_MODEL + d];
        Ks[r][d] = Kbase[(size_t)r * D_MODEL + d];
    }
    __syncthreads();
    int tx = tid & 15, ty = tid >> 4;
    float acc[2][2] = {};
    #pragma unroll 8
    for (int d = 0; d < 64; d++) {
        float a0 = Qs[ty * 2][d],     a1 = Qs[ty * 2 + 1][d];
        float b0 = Ks[tx * 2][d],     b1 = Ks[tx * 2 + 1][d];
        acc[0][0] = fmaf(a0, b0, acc[0][0]);
        acc[0][1] = fmaf(a0, b1, acc[0][1]);
        acc[1][0] = fmaf(a1, b0, acc[1][0]);
        acc[1][1] = fmaf(a1, b1, acc[1][1]);
    }
    #pragma unroll
    for (int i = 0; i < 2; i++)
        #pragma unroll
        for (int j = 0; j < 2; j++) {
            int qq = q0 + ty * 2 + i;
            int kk = k0 + tx * 2 + j;
            float v = acc[i][j] * 0.125f;   // 1/sqrt(64)
            if (causal && kk > qq) v = -1e30f;
            Sc[((size_t)bh * SEQ + qq) * SEQ + kk] = v;
        }
}

// ---------------- row softmax over 512 (in place) --------------------------
__global__ __launch_bounds__(256) void softmax_row_kernel(float* __restrict__ Sc)
{
    __shared__ float lds[4];
    size_t row = blockIdx.x;
    float* p = Sc + row * SEQ;
    int tid = threadIdx.x;
    float v0 = p[tid], v1 = p[tid + 256];
    float m = block_max(fmaxf(v0, v1), lds);
    float e0 = expf(v0 - m), e1 = expf(v1 - m);
    float s = block_sum(e0 + e1, lds);
    float inv = 1.f / s;
    p[tid] = e0 * inv;
    p[tid + 256] = e1 * inv;
}

// ---------------- O(bh, q, :) = W(q,k) @ V(k, d), f16 out ------------------
__global__ __launch_bounds__(256) void attn_av_kernel(
    const float* __restrict__ Sc, const float* __restrict__ V,
    f16* __restrict__ O16)
{
    __shared__ float Ws[32][33];
    __shared__ float Vs[32][65];
    int bh = blockIdx.y;
    int b = bh >> 4, h = bh & 15;
    int q0 = blockIdx.x * 32;
    int tid = threadIdx.x;
    int tx = tid & 15, ty = tid >> 4;
    float acc[2][4] = {};
    for (int k0 = 0; k0 < SEQ; k0 += 32) {
        #pragma unroll
        for (int e = 0; e < 4; e++) {
            int idx = tid + e * 256;
            int r = idx >> 5, c = idx & 31;
            Ws[r][c] = Sc[((size_t)bh * SEQ + q0 + r) * SEQ + k0 + c];
        }
        #pragma unroll
        for (int e = 0; e < 8; e++) {
            int idx = tid + e * 256;
            int r = idx >> 6, d = idx & 63;
            Vs[r][d] = V[(size_t)(b * SEQ + k0 + r) * D_MODEL + h * HDIM + d];
        }
        __syncthreads();
        #pragma unroll
        for (int kk = 0; kk < 32; kk++) {
            float a0 = Ws[ty * 2][kk], a1 = Ws[ty * 2 + 1][kk];
            float bv[4];
            #pragma unroll
            for (int j = 0; j < 4; j++) bv[j] = Vs[kk][tx * 4 + j];
            #pragma unroll
            for (int j = 0; j < 4; j++) {
                acc[0][j] = fmaf(a0, bv[j], acc[0][j]);
                acc[1][j] = fmaf(a1, bv[j], acc[1][j]);
            }
        }
        __syncthreads();
    }
    #pragma unroll
    for (int i = 0; i < 2; i++)
        #pragma unroll
        for (int j = 0; j < 4; j++)
            O16[(size_t)(b * SEQ + q0 + ty * 2 + i) * D_MODEL + h * HDIM + tx * 4 + j]
                = (f16)acc[i][j];
}

// ---------------- fused residual add + LayerNorm (f32 + f16 out) -----------
__global__ __launch_bounds__(256) void add_ln_kernel(
    const float* __restrict__ X, const float* __restrict__ Y,
    const float* __restrict__ g, const float* __restrict__ bb,
    float* __restrict__ Out, f16* __restrict__ Out16)
{
    __shared__ float lds[4];
    int row = blockIdx.x;
    const float* xp = X + (size_t)row * D_MODEL;
    const float* yp = Y + (size_t)row * D_MODEL;
    int tid = threadIdx.x;
    float s[4];
    float lsum = 0.f;
    #pragma unroll
    for (int e = 0; e < 4; e++) {
        int d = tid + e * 256;
        s[e] = xp[d] + yp[d];
        lsum += s[e];
    }
    float mu = block_sum(lsum, lds) * (1.f / D_MODEL);
    float lv = 0.f;
    #pragma unroll
    for (int e = 0; e < 4; e++) { float t = s[e] - mu; lv += t * t; }
    float rstd = rsqrtf(block_sum(lv, lds) * (1.f / D_MODEL) + 1e-5f);
    #pragma unroll
    for (int e = 0; e < 4; e++) {
        int d = tid + e * 256;
        float v = (s[e] - mu) * rstd * g[d] + bb[d];
        Out[(size_t)row * D_MODEL + d] = v;
        Out16[(size_t)row * D_MODEL + d] = (f16)v;
    }
}

// ---------------- softmax over axis 0 (batch of 4), vocab-chunked ----------
__global__ __launch_bounds__(256) void softmax_axis0_chunk_kernel(
    const float* __restrict__ L, float* __restrict__ out, int cv0)
{
    int idx = blockIdx.x * 256 + threadIdx.x;     // over SEQ*VCHUNK
    if (idx >= SEQ * VCHUNK) return;
    int s = idx / VCHUNK;
    int c = idx - s * VCHUNK;
    float v0 = L[((size_t)(0 * SEQ + s)) * VCHUNK + c];
    float v1 = L[((size_t)(1 * SEQ + s)) * VCHUNK + c];
    float v2 = L[((size_t)(2 * SEQ + s)) * VCHUNK + c];
    float v3 = L[((size_t)(3 * SEQ + s)) * VCHUNK + c];
    float m = fmaxf(fmaxf(v0, v1), fmaxf(v2, v3));
    float e0 = expf(v0 - m), e1 = expf(v1 - m), e2 = expf(v2 - m), e3 = expf(v3 - m);
    float inv = 1.f / (e0 + e1 + e2 + e3);
    out[((size_t)(0 * SEQ + s)) * VOCAB + cv0 + c] = e0 * inv;
    out[((size_t)(1 * SEQ + s)) * VOCAB + cv0 + c] = e1 * inv;
    out[((size_t)(2 * SEQ + s)) * VOCAB + cv0 + c] = e2 * inv;
    out[((size_t)(3 * SEQ + s)) * VOCAB + cv0 + c] = e3 * inv;
}

// ===========================================================================
extern "C" void kernel_launch(void* const* d_in, const int* in_sizes, int n_in,
                              void* d_out, int out_size, void* d_ws, size_t ws_size,
                              hipStream_t stream)
{
    const int*   text = (const int*)d_in[0];
    const float* enc  = (const float*)d_in[1];
    const float* W_e  = (const float*)d_in[2];
    const float* b_out= (const float*)d_in[3];
    const float* ln_g = (const float*)d_in[4];
    const float* ln_b = (const float*)d_in[5];
    const float* W1   = (const float*)d_in[6];
    const float* b1   = (const float*)d_in[7];
    const float* W2   = (const float*)d_in[8];
    const float* b2   = (const float*)d_in[9];
    const float* mWq  = (const float*)d_in[10]; const float* mbq = (const float*)d_in[11];
    const float* mWk  = (const float*)d_in[12]; const float* mbk = (const float*)d_in[13];
    const float* mWv  = (const float*)d_in[14]; const float* mbv = (const float*)d_in[15];
    const float* mWo  = (const float*)d_in[16]; const float* mbo = (const float*)d_in[17];
    const float* cWq  = (const float*)d_in[18]; const float* cbq = (const float*)d_in[19];
    const float* cWk  = (const float*)d_in[20]; const float* cbk = (const float*)d_in[21];
    const float* cWv  = (const float*)d_in[22]; const float* cbv = (const float*)d_in[23];
    const float* cWo  = (const float*)d_in[24]; const float* cbo = (const float*)d_in[25];
    float* out = (float*)d_out;

    // ---- workspace layout (250.5 MiB total; 258 MiB proven available) ----
    char* w8 = (char*)d_ws;
    float* x    = (float*)(w8 +   0 * (size_t)MiB);
    float* q    = (float*)(w8 +   8 * (size_t)MiB);
    float* kbuf = (float*)(w8 +  16 * (size_t)MiB);  // aliased by o
    float* vbuf = (float*)(w8 +  24 * (size_t)MiB);  // aliased by a
    float* c    = (float*)(w8 +  32 * (size_t)MiB);
    float* enck = (float*)(w8 +  40 * (size_t)MiB);
    float* encv = (float*)(w8 +  48 * (size_t)MiB);
    float* Sc   = (float*)(w8 +  56 * (size_t)MiB);  // 64 MiB; logits chunk aliases
    float* o = kbuf;      // kbuf dead after scores; o live until add_ln
    float* a = vbuf;      // vbuf dead after AV; a live until cross add_ln
    float* logits = Sc;   // Sc dead after last layer; chunk = 50 MiB

    f16* x16    = (f16*)(w8 + 120 * (size_t)MiB);
    f16* a16    = (f16*)(w8 + 124 * (size_t)MiB);
    f16* c16    = (f16*)(w8 + 128 * (size_t)MiB);
    f16* attn16 = (f16*)(w8 + 132 * (size_t)MiB);
    f16* enc16  = (f16*)(w8 + 136 * (size_t)MiB);
    f16* ffh16  = (f16*)(w8 + 140 * (size_t)MiB);    // 16 MiB
    f16* mWq16  = (f16*)(w8 + 156 * (size_t)MiB);
    f16* mWk16  = (f16*)(w8 + 158 * (size_t)MiB);
    f16* mWv16  = (f16*)(w8 + 160 * (size_t)MiB);
    f16* mWo16  = (f16*)(w8 + 162 * (size_t)MiB);
    f16* cWq16  = (f16*)(w8 + 164 * (size_t)MiB);
    f16* cWk16  = (f16*)(w8 + 166 * (size_t)MiB);
    f16* cWv16  = (f16*)(w8 + 168 * (size_t)MiB);
    f16* cWo16  = (f16*)(w8 + 170 * (size_t)MiB);
    f16* W116   = (f16*)(w8 + 172 * (size_t)MiB);    // 8 MiB
    f16* W216   = (f16*)(w8 + 180 * (size_t)MiB);    // 8 MiB
    f16* We16   = (f16*)(w8 + 188 * (size_t)MiB);    // 62.5 MiB

    auto conv = [&](const float* src, f16* dst, int n) {
        f32_to_f16_kernel<<<(n + 1023) / 1024, 256, 0, stream>>>(src, dst, n);
    };
    auto gemm32 = [&](const f16* A, const f16* Wt, const float* bias, float* C,
                      int M, int N, int K) {
        gemm16_kernel<false, 0><<<dim3(N / 128, M / 128), 256, 0, stream>>>(
            A, Wt, bias, C, nullptr, M, N, K);
    };

    // ---- weight / encoder conversion (every call; graph-safe) ----
    const int DD = D_MODEL * D_MODEL;
    conv(mWq, mWq16, DD); conv(mWk, mWk16, DD); conv(mWv, mWv16, DD); conv(mWo, mWo16, DD);
    conv(cWq, cWq16, DD); conv(cWk, cWk16, DD); conv(cWv, cWv16, DD); conv(cWo, cWo16, DD);
    conv(W1, W116, FFDIM * D_MODEL); conv(W2, W216, FFDIM * D_MODEL);
    conv(W_e, We16, VOCAB * D_MODEL);
    conv(enc, enc16, NTOK * D_MODEL);

    // ---- embed + posenc ----
    embed_kernel<<<NTOK, 256, 0, stream>>>(text, W_e, x, x16);

    // ---- encoder K/V (fixed across layers) ----
    gemm32(enc16, cWk16, cbk, enck, NTOK, D_MODEL, D_MODEL);
    gemm32(enc16, cWv16, cbv, encv, NTOK, D_MODEL, D_MODEL);

    const int BH = NBATCH * NHEAD;   // 64
    for (int layer = 0; layer < 6; layer++) {
        // --- self attention (causal) ---
        gemm32(x16, mWq16, mbq, q,    NTOK, D_MODEL, D_MODEL);
        gemm32(x16, mWk16, mbk, kbuf, NTOK, D_MODEL, D_MODEL);
        gemm32(x16, mWv16, mbv, vbuf, NTOK, D_MODEL, D_MODEL);
        attn_scores_kernel<<<dim3(SEQ / 32, SEQ / 32, BH), 256, 0, stream>>>(q, kbuf, Sc, 1);
        softmax_row_kernel<<<BH * SEQ, 256, 0, stream>>>(Sc);
        attn_av_kernel<<<dim3(SEQ / 32, BH), 256, 0, stream>>>(Sc, vbuf, attn16);
        gemm32(attn16, mWo16, mbo, o, NTOK, D_MODEL, D_MODEL);
        add_ln_kernel<<<NTOK, 256, 0, stream>>>(x, o, ln_g, ln_b, a, a16);

        // --- cross attention ---
        gemm32(a16, cWq16, cbq, q, NTOK, D_MODEL, D_MODEL);
        attn_scores_kernel<<<dim3(SEQ / 32, SEQ / 32, BH), 256, 0, stream>>>(q, enck, Sc, 0);
        softmax_row_kernel<<<BH * SEQ, 256, 0, stream>>>(Sc);
        attn_av_kernel<<<dim3(SEQ / 32, BH), 256, 0, stream>>>(Sc, encv, attn16);
        gemm32(attn16, cWo16, cbo, o, NTOK, D_MODEL, D_MODEL);
        add_ln_kernel<<<NTOK, 256, 0, stream>>>(o, a, ln_g, ln_b, c, c16);

        // --- FFN ---
        gemm16_kernel<true, 1><<<dim3(FFDIM / 128, NTOK / 128), 256, 0, stream>>>(
            c16, W116, b1, nullptr, ffh16, NTOK, FFDIM, D_MODEL);
        gemm32(ffh16, W216, b2, o, NTOK, D_MODEL, FFDIM);
        add_ln_kernel<<<NTOK, 256, 0, stream>>>(c, o, ln_g, ln_b, x, x16);
    }

    // ---- final logits (vocab-chunked) + axis-0 softmax ----
    for (int ch = 0; ch < VOCAB / VCHUNK; ch++) {
        int cv0 = ch * VCHUNK;
        gemm32(x16, We16 + (size_t)cv0 * D_MODEL, b_out + cv0, logits,
               NTOK, VCHUNK, D_MODEL);
        softmax_axis0_chunk_kernel<<<(SEQ * VCHUNK + 255) / 256, 256, 0, stream>>>(
            logits, out, cv0);
    }
}